// Round 1
// baseline (549.443 us; speedup 1.0000x reference)
//
#include <hip/hip_runtime.h>
#include <math.h>

// LocalSpatialEncoding: out[n,k,:] = [ MLP(concat(o, nb, o-nb, |o-nb|)) , features[n] ]
//   MLP: relu(c @ W1 + b1) @ W2 + b2,  c:10, hidden:32, D:64
// One thread per (n,k) pair. Weights in LDS (broadcast reads). Write-BW-bound.

#define HID 32
#define DF  64

__global__ __launch_bounds__(256) void lse_kernel(
    const float* __restrict__ coords,    // (N,3)
    const float* __restrict__ features,  // (N,64)
    const float* __restrict__ W1,        // (10,32)
    const float* __restrict__ b1,        // (32,)
    const float* __restrict__ W2,        // (32,64)
    const float* __restrict__ b2,        // (64,)
    const int*   __restrict__ nidx,      // (N,K) as int32
    float* __restrict__ out,             // (N,K,128)
    long long total, int K)
{
    __shared__ float sW1[10 * HID];
    __shared__ float sb1[HID];
    __shared__ float sW2[HID * DF];
    __shared__ float sb2[DF];

    const int t = threadIdx.x;
    for (int i = t; i < 10 * HID; i += 256) sW1[i] = W1[i];
    for (int i = t; i < HID * DF; i += 256) sW2[i] = W2[i];
    if (t < HID) sb1[t] = b1[t];
    if (t < DF)  sb2[t] = b2[t];
    __syncthreads();

    const long long p = (long long)blockIdx.x * 256 + t;
    if (p >= total) return;
    const int n = (int)(p / K);
    const int j = nidx[p];

    const float ox = coords[3 * n + 0];
    const float oy = coords[3 * n + 1];
    const float oz = coords[3 * n + 2];
    const float nx = coords[3 * j + 0];
    const float ny = coords[3 * j + 1];
    const float nz = coords[3 * j + 2];
    const float rx = ox - nx, ry = oy - ny, rz = oz - nz;
    const float dist = sqrtf(rx * rx + ry * ry + rz * rz);

    float c[10] = {ox, oy, oz, nx, ny, nz, rx, ry, rz, dist};

    // h = relu(c @ W1 + b1)
    float h[HID];
#pragma unroll
    for (int jj = 0; jj < HID; ++jj) {
        float acc = sb1[jj];
#pragma unroll
        for (int cc = 0; cc < 10; ++cc) acc = fmaf(c[cc], sW1[cc * HID + jj], acc);
        h[jj] = fmaxf(acc, 0.0f);
    }

    float* orow = out + p * (2 * DF);

    // enc = h @ W2 + b2, written 4 at a time
#pragma unroll
    for (int d0 = 0; d0 < DF; d0 += 4) {
        float a0 = sb2[d0 + 0];
        float a1 = sb2[d0 + 1];
        float a2 = sb2[d0 + 2];
        float a3 = sb2[d0 + 3];
#pragma unroll
        for (int jj = 0; jj < HID; ++jj) {
            const float hv = h[jj];
            a0 = fmaf(hv, sW2[jj * DF + d0 + 0], a0);
            a1 = fmaf(hv, sW2[jj * DF + d0 + 1], a1);
            a2 = fmaf(hv, sW2[jj * DF + d0 + 2], a2);
            a3 = fmaf(hv, sW2[jj * DF + d0 + 3], a3);
        }
        float4 v = make_float4(a0, a1, a2, a3);
        *reinterpret_cast<float4*>(orow + d0) = v;
    }

    // features half: out[n,k,64:128] = features[n,:]
    const float4* f4 = reinterpret_cast<const float4*>(features + (long long)n * DF);
    float4* o4 = reinterpret_cast<float4*>(orow + DF);
#pragma unroll
    for (int d0 = 0; d0 < DF / 4; ++d0) o4[d0] = f4[d0];
}

extern "C" void kernel_launch(void* const* d_in, const int* in_sizes, int n_in,
                              void* d_out, int out_size, void* d_ws, size_t ws_size,
                              hipStream_t stream) {
    const float* coords   = (const float*)d_in[0];
    const float* features = (const float*)d_in[1];
    const float* W1       = (const float*)d_in[2];
    const float* b1       = (const float*)d_in[3];
    const float* W2       = (const float*)d_in[4];
    const float* b2       = (const float*)d_in[5];
    const int*   nidx     = (const int*)d_in[6];

    const int N = in_sizes[0] / 3;              // coords (N,3)
    const int K = in_sizes[6] / N;              // neighbor_idx (N,K)
    const long long total = (long long)N * K;

    float* out = (float*)d_out;

    const int block = 256;
    const long long grid = (total + block - 1) / block;
    lse_kernel<<<(unsigned)grid, block, 0, stream>>>(
        coords, features, W1, b1, W2, b2, nidx, out, total, K);
}

// Round 3
// 330.941 us; speedup vs baseline: 1.6602x; 1.6602x over previous
//
#include <hip/hip_runtime.h>
#include <math.h>

// LocalSpatialEncoding: out[p=(n,k), :] = [ MLP(concat(o, nb, o-nb, |o-nb|)) , features[n] ]
//   MLP: relu(c @ W1 + b1) @ W2 + b2,  c:10, hidden:32, D:64. Output row = 128 f32 = 512 B.
//
// Write-BW-bound. Key structure: 8 lanes cooperate per row so every store
// instruction's 8-lane group writes one FULL 128 B cache line (4 float4 x 8
// lanes = 512 B row in 4 line-complete instructions). This eliminates the
// partial-dirty-line write amplification seen in round 1 (WRITE_SIZE 2.5x).

#define HID 32
#define DF  64

typedef float f4 __attribute__((ext_vector_type(4)));  // native vec for nontemporal builtins

__global__ __launch_bounds__(256) void lse_kernel(
    const float* __restrict__ coords,    // (N,3)
    const float* __restrict__ features,  // (N,64)
    const float* __restrict__ W1,        // (10,32)
    const float* __restrict__ b1,        // (32,)
    const float* __restrict__ W2,        // (32,64)
    const float* __restrict__ b2,        // (64,)
    const int*   __restrict__ nidx,      // (N,K)
    float* __restrict__ out,             // (N,K,128)
    long long total, int K)
{
    __shared__ float sW1[10 * HID];
    __shared__ float sb1[HID];
    __shared__ float sW2[HID * DF];
    __shared__ float sb2[DF];

    const int t = threadIdx.x;
    for (int i = t; i < 10 * HID; i += 256) sW1[i] = W1[i];
    for (int i = t; i < HID * DF; i += 256) sW2[i] = W2[i];
    if (t < HID) sb1[t] = b1[t];
    if (t < DF)  sb2[t] = b2[t];
    __syncthreads();

    const int grp = t >> 3;          // 0..31: row group within block
    const int s   = t & 7;           // 0..7 : lane within group
    const long long p = (long long)blockIdx.x * 32 + grp;
    if (p >= total) return;

    const int n = (int)(p / K);
    const int j = nidx[p];

    const float ox = coords[3 * n + 0];
    const float oy = coords[3 * n + 1];
    const float oz = coords[3 * n + 2];
    const float nx = coords[3 * j + 0];
    const float ny = coords[3 * j + 1];
    const float nz = coords[3 * j + 2];
    const float rx = ox - nx, ry = oy - ny, rz = oz - nz;
    const float dist = sqrtf(rx * rx + ry * ry + rz * rz);

    const float c[10] = {ox, oy, oz, nx, ny, nz, rx, ry, rz, dist};

    // h = relu(c @ W1 + b1)  (computed redundantly by all 8 lanes of the group)
    float h[HID];
#pragma unroll
    for (int jj = 0; jj < HID; ++jj) {
        float acc = sb1[jj];
#pragma unroll
        for (int cc = 0; cc < 10; ++cc) acc = fmaf(c[cc], sW1[cc * HID + jj], acc);
        h[jj] = fmaxf(acc, 0.0f);
    }

    // Lane s computes enc columns {4s..4s+3} and {32+4s..32+4s+3}.
    const int cA = 4 * s;
    const int cB = 32 + 4 * s;
    float a0 = sb2[cA + 0], a1 = sb2[cA + 1], a2 = sb2[cA + 2], a3 = sb2[cA + 3];
    float e0 = sb2[cB + 0], e1 = sb2[cB + 1], e2 = sb2[cB + 2], e3 = sb2[cB + 3];
#pragma unroll
    for (int jj = 0; jj < HID; ++jj) {
        const float hv = h[jj];
        const float* w = sW2 + jj * DF;
        a0 = fmaf(hv, w[cA + 0], a0);
        a1 = fmaf(hv, w[cA + 1], a1);
        a2 = fmaf(hv, w[cA + 2], a2);
        a3 = fmaf(hv, w[cA + 3], a3);
        e0 = fmaf(hv, w[cB + 0], e0);
        e1 = fmaf(hv, w[cB + 1], e1);
        e2 = fmaf(hv, w[cB + 2], e2);
        e3 = fmaf(hv, w[cB + 3], e3);
    }

    float* orow = out + p * (2 * DF);

    // Each store below: 8 lanes x 16 B = one full 128 B line per group.
    f4 va = {a0, a1, a2, a3};
    f4 ve = {e0, e1, e2, e3};
    __builtin_nontemporal_store(va, reinterpret_cast<f4*>(orow + cA));
    __builtin_nontemporal_store(ve, reinterpret_cast<f4*>(orow + cB));

    // features half: out[p, 64:128] = features[n, :]
    const float* frow = features + (long long)n * DF;
    const f4 f0 = *reinterpret_cast<const f4*>(frow + cA);
    const f4 f1 = *reinterpret_cast<const f4*>(frow + cB);
    __builtin_nontemporal_store(f0, reinterpret_cast<f4*>(orow + DF + cA));
    __builtin_nontemporal_store(f1, reinterpret_cast<f4*>(orow + DF + cB));
}

extern "C" void kernel_launch(void* const* d_in, const int* in_sizes, int n_in,
                              void* d_out, int out_size, void* d_ws, size_t ws_size,
                              hipStream_t stream) {
    const float* coords   = (const float*)d_in[0];
    const float* features = (const float*)d_in[1];
    const float* W1       = (const float*)d_in[2];
    const float* b1       = (const float*)d_in[3];
    const float* W2       = (const float*)d_in[4];
    const float* b2       = (const float*)d_in[5];
    const int*   nidx     = (const int*)d_in[6];

    const int N = in_sizes[0] / 3;              // coords (N,3)
    const int K = in_sizes[6] / N;              // neighbor_idx (N,K)
    const long long total = (long long)N * K;

    float* out = (float*)d_out;

    const int block = 256;                      // 32 rows per block (8 lanes/row)
    const long long grid = (total + 31) / 32;
    lse_kernel<<<(unsigned)grid, block, 0, stream>>>(
        coords, features, W1, b1, W2, b2, nidx, out, total, K);
}

// Round 4
// 175.262 us; speedup vs baseline: 3.1350x; 1.8883x over previous
//
#include <hip/hip_runtime.h>
#include <math.h>

// LocalSpatialEncoding: out[p=(n,k), :] = [ MLP(concat(o, nb, o-nb, |o-nb|)) , features[n] ]
//   MLP: relu(c @ W1 + b1) @ W2 + b2,  c:10, hidden:32, D:64. Row = 128 f32 = 512 B.
//
// Structure (round 4):
//  - 1 thread per row (no redundant compute; 25k waves total).
//  - Weights read from GLOBAL with wave-uniform indices -> compiler emits s_load
//    (scalar pipe + sK$), zero VALU/LDS issue cost for weights.
//  - enc half staged in wave-private LDS (row stride 68 floats: 16B-aligned,
//    bank-spread), then stored 4 rows/iter with 16 lanes x float4 = 256 B
//    contiguous -> every 128 B line fully written (no partial-line write amp).
//  - features half: global->global with the same line-complete 16-lane pattern.

#define HID 32
#define DF  64
#define RS  68   // LDS row stride in floats (64 + 4 pad)

typedef float f4 __attribute__((ext_vector_type(4)));

__global__ __launch_bounds__(256) void lse_kernel(
    const float* __restrict__ coords,    // (N,3)
    const float* __restrict__ features,  // (N,64)
    const float* __restrict__ W1,        // (10,32)
    const float* __restrict__ b1,        // (32,)
    const float* __restrict__ W2,        // (32,64)
    const float* __restrict__ b2,        // (64,)
    const int*   __restrict__ nidx,      // (N,K)
    float* __restrict__ out,             // (N,K,128)
    long long total, int K, int kshift)
{
    __shared__ float smem[4][64][RS];    // 69.6 KB: wave-private 64-row enc tiles

    const int t  = threadIdx.x;
    const int wv = t >> 6;
    const int l  = t & 63;
    const long long pbase = (long long)blockIdx.x * 256 + (long long)wv * 64;
    const long long p = pbase + l;

    if (p < total) {
        const int n = (kshift >= 0) ? (int)(p >> kshift) : (int)(p / K);
        const int j = nidx[p];

        const float ox = coords[3 * n + 0];
        const float oy = coords[3 * n + 1];
        const float oz = coords[3 * n + 2];
        const float nx = coords[3 * j + 0];
        const float ny = coords[3 * j + 1];
        const float nz = coords[3 * j + 2];
        const float rx = ox - nx, ry = oy - ny, rz = oz - nz;
        const float dist = sqrtf(rx * rx + ry * ry + rz * rz);
        const float c[10] = {ox, oy, oz, nx, ny, nz, rx, ry, rz, dist};

        // h = relu(c @ W1 + b1). W1/b1 indices compile-time -> s_load.
        float h[HID];
#pragma unroll
        for (int jj = 0; jj < HID; ++jj) {
            float acc = b1[jj];
#pragma unroll
            for (int cc = 0; cc < 10; ++cc) acc = fmaf(c[cc], W1[cc * HID + jj], acc);
            h[jj] = fmaxf(acc, 0.0f);
        }

        // enc = h @ W2 + b2, 4 columns at a time -> LDS. c0 wave-uniform.
        for (int c0 = 0; c0 < DF; c0 += 4) {
            float a0 = b2[c0 + 0], a1 = b2[c0 + 1], a2 = b2[c0 + 2], a3 = b2[c0 + 3];
#pragma unroll
            for (int jj = 0; jj < HID; ++jj) {
                const float hv = h[jj];
                const float* w = W2 + jj * DF + c0;   // uniform addr -> s_load
                a0 = fmaf(hv, w[0], a0);
                a1 = fmaf(hv, w[1], a1);
                a2 = fmaf(hv, w[2], a2);
                a3 = fmaf(hv, w[3], a3);
            }
            f4 v = {a0, a1, a2, a3};
            *reinterpret_cast<f4*>(&smem[wv][l][c0]) = v;
        }
    }

    __syncthreads();

    // Store phase: 16 iters x 4 rows; 16 lanes cover one row's 256 B half.
    const int g = l >> 4;    // row group 0..3
    const int q = l & 15;    // float4 slot within 256 B
#pragma unroll 4
    for (int i = 0; i < 16; ++i) {
        const int r = 4 * i + g;
        const long long pr = pbase + r;
        if (pr < total) {
            float* orow = out + pr * (2 * DF);
            // enc half: LDS -> global (line-complete)
            const f4 enc = *reinterpret_cast<const f4*>(&smem[wv][r][4 * q]);
            __builtin_nontemporal_store(enc, reinterpret_cast<f4*>(orow + 4 * q));
            // features half: global -> global (line-complete)
            const int nr = (kshift >= 0) ? (int)(pr >> kshift) : (int)(pr / K);
            const f4 f = *reinterpret_cast<const f4*>(features + (long long)nr * DF + 4 * q);
            __builtin_nontemporal_store(f, reinterpret_cast<f4*>(orow + DF + 4 * q));
        }
    }
}

extern "C" void kernel_launch(void* const* d_in, const int* in_sizes, int n_in,
                              void* d_out, int out_size, void* d_ws, size_t ws_size,
                              hipStream_t stream) {
    const float* coords   = (const float*)d_in[0];
    const float* features = (const float*)d_in[1];
    const float* W1       = (const float*)d_in[2];
    const float* b1       = (const float*)d_in[3];
    const float* W2       = (const float*)d_in[4];
    const float* b2       = (const float*)d_in[5];
    const int*   nidx     = (const int*)d_in[6];

    const int N = in_sizes[0] / 3;              // coords (N,3)
    const int K = in_sizes[6] / N;              // neighbor_idx (N,K)
    const long long total = (long long)N * K;
    const int kshift = ((K & (K - 1)) == 0) ? __builtin_ctz(K) : -1;

    float* out = (float*)d_out;

    const int block = 256;                      // 4 waves x 64 rows = 256 rows/block
    const long long grid = (total + 255) / 256;
    lse_kernel<<<(unsigned)grid, block, 0, stream>>>(
        coords, features, W1, b1, W2, b2, nidx, out, total, K, kshift);
}